// Round 7
// baseline (3620.643 us; speedup 1.0000x reference)
//
#include <hip/hip_runtime.h>
#include <math.h>

// Problem constants (fixed by setup_inputs): B=8, N=M=8192, D=3, fp32.
// Exact chamfer via uniform-grid binning + WAVE-COOPERATIVE box-expansion NN:
// one wave per 64 consecutive sorted queries; all cell/point loads are
// wave-uniform (broadcast), each lane mins against its own query.
#define BB 8
#define NPTS 8192
#define NSIDE (BB * NPTS)     // 65536 points per side
#define NTOT (2 * NSIDE)      // 131072 (both sides)

#define BLOCK 256
#define GRID_LO (-3.8f)
#define GRID_HI (3.8f)

__device__ __forceinline__ int cell_of(float x, float lo, float invw, int G) {
    int c = (int)((x - lo) * invw);
    return min(G - 1, max(0, c));
}

// ---- 1. count points per fine cell and per coarse 4^3 block ----
__global__ __launch_bounds__(BLOCK) void bin_count(
        const float* __restrict__ pred, const float* __restrict__ tgt,
        int* __restrict__ counts, int* __restrict__ ccoarse,
        int G, int G3, int Gc, int Gc3, float lo, float invw) {
    int i = blockIdx.x * BLOCK + threadIdx.x;      // 0..NTOT-1
    int side = i >> 16;
    int local = i & (NSIDE - 1);
    int sb = i >> 13;                              // side*8 + batch
    const float* src = side ? tgt : pred;
    float x = src[(size_t)local * 3 + 0];
    float y = src[(size_t)local * 3 + 1];
    float z = src[(size_t)local * 3 + 2];
    int cx = cell_of(x, lo, invw, G);
    int cy = cell_of(y, lo, invw, G);
    int cz = cell_of(z, lo, invw, G);
    atomicAdd(&counts[(size_t)sb * G3 + (cz * G + cy) * G + cx], 1);
    atomicAdd(&ccoarse[(size_t)sb * Gc3 + ((cz >> 2) * Gc + (cy >> 2)) * Gc + (cx >> 2)], 1);
}

// ---- 2. per-(side,batch) exclusive scan of cell counts -> start, cursor ----
__global__ __launch_bounds__(1024) void scan_cells(
        const int* __restrict__ counts, int* __restrict__ cstart,
        int* __restrict__ ccur, int G3) {
    const int sb = blockIdx.x;                     // side*8 + b
    const int b = sb & 7;
    const size_t base0 = (size_t)sb * G3;
    const int t = threadIdx.x;
    __shared__ int buf[1024];
    __shared__ int sbase;
    if (t == 0) sbase = b * NPTS;                  // global base in sorted array
    __syncthreads();
    for (int c0 = 0; c0 < G3; c0 += 1024) {
        int idx = c0 + t;
        int v = (idx < G3) ? counts[base0 + idx] : 0;
        buf[t] = v;
        __syncthreads();
        for (int s = 1; s < 1024; s <<= 1) {       // Hillis-Steele inclusive
            int x = (t >= s) ? buf[t - s] : 0;
            __syncthreads();
            buf[t] += x;
            __syncthreads();
        }
        int w = sbase + buf[t] - v;                // exclusive + running base
        if (idx < G3) { cstart[base0 + idx] = w; ccur[base0 + idx] = w; }
        __syncthreads();
        if (t == 0) sbase += buf[1023];
        __syncthreads();
    }
}

// ---- 3. scatter points into per-cell contiguous storage (x,y,z,|p|^2) ----
__global__ __launch_bounds__(BLOCK) void bin_scatter(
        const float* __restrict__ pred, const float* __restrict__ tgt,
        int* __restrict__ ccur, float4* __restrict__ sortedP,
        float4* __restrict__ sortedT, int G, int G3, float lo, float invw) {
    int i = blockIdx.x * BLOCK + threadIdx.x;
    int side = i >> 16;
    int local = i & (NSIDE - 1);
    int sb = i >> 13;
    const float* src = side ? tgt : pred;
    float x = src[(size_t)local * 3 + 0];
    float y = src[(size_t)local * 3 + 1];
    float z = src[(size_t)local * 3 + 2];
    int c = (cell_of(z, lo, invw, G) * G + cell_of(y, lo, invw, G)) * G
            + cell_of(x, lo, invw, G);
    int pos = atomicAdd(&ccur[(size_t)sb * G3 + c], 1);   // cursor -> end ptr
    float w = fmaf(x, x, fmaf(y, y, z * z));
    float4 v = make_float4(x, y, z, w);
    if (side) sortedT[pos] = v; else sortedP[pos] = v;
}

// ---- 3b. fuse (start,end) into one int2 per cell (halves metadata loads) ----
__global__ __launch_bounds__(BLOCK) void build_meta(
        const int* __restrict__ cstart, const int* __restrict__ ccur,
        int2* __restrict__ cmeta, int total) {
    int i = blockIdx.x * BLOCK + threadIdx.x;
    if (i < total) cmeta[i] = make_int2(cstart[i], ccur[i]);
}

// ---- 4. wave-cooperative exact NN ----
// Wave = 64 consecutive sorted queries (spatially compact). Box = cell-space
// bounding box of the wave's queries. Scan cells by increasing box-Chebyshev
// distance; a point in an unscanned cell (dist > k) is >= k*W from every
// in-box query, so the wave stops when k*W >= every lane's current best.
// All metadata/point loads are wave-uniform (broadcast); per-lane work is
// 3 v_fma + 1 v_min per candidate point. Coarse blocks (4^3 cells) with
// zero points are skipped with a single load.
__global__ __launch_bounds__(BLOCK) void query_min(
        const float4* __restrict__ sortedP, const float4* __restrict__ sortedT,
        const int2* __restrict__ cmeta, const int* __restrict__ ccoarse,
        float* __restrict__ dmin, int G, int G3, int Gc, int Gc3,
        float lo, float W, float invw) {
    int i = blockIdx.x * BLOCK + threadIdx.x;
    int side = i >> 16;
    int local = i & (NSIDE - 1);
    int b = local >> 13;
    const float4* __restrict__ Q = side ? sortedT : sortedP;
    const float4* __restrict__ T = side ? sortedP : sortedT;
    int tb = side ? b : (8 + b);                   // target side's (side,b)
    const int2* __restrict__ META = cmeta + (size_t)tb * G3;
    const int* __restrict__ CO = ccoarse + (size_t)tb * Gc3;

    float4 q = Q[local];
    float nx = -2.0f * q.x, ny = -2.0f * q.y, nz = -2.0f * q.z, wq = q.w;
    int cx = cell_of(q.x, lo, invw, G);
    int cy = cell_of(q.y, lo, invw, G);
    int cz = cell_of(q.z, lo, invw, G);

    // Wave bounding box in cell coords (queries are sorted -> compact).
    int bx0 = cx, bx1 = cx, by0 = cy, by1 = cy, bz0 = cz, bz1 = cz;
    #pragma unroll
    for (int off = 32; off; off >>= 1) {
        bx0 = min(bx0, __shfl_xor(bx0, off));
        bx1 = max(bx1, __shfl_xor(bx1, off));
        by0 = min(by0, __shfl_xor(by0, off));
        by1 = max(by1, __shfl_xor(by1, off));
        bz0 = min(bz0, __shfl_xor(bz0, off));
        bz1 = max(bz1, __shfl_xor(bz1, off));
    }
    bx0 = __builtin_amdgcn_readfirstlane(bx0);
    bx1 = __builtin_amdgcn_readfirstlane(bx1);
    by0 = __builtin_amdgcn_readfirstlane(by0);
    by1 = __builtin_amdgcn_readfirstlane(by1);
    bz0 = __builtin_amdgcn_readfirstlane(bz0);
    bz1 = __builtin_amdgcn_readfirstlane(bz1);

    float best = INFINITY;                         // min of (|t|^2 - 2 q.t)
    int km = -1;                                   // scanned dilation so far
    int tneed = 1;                                 // scan out to this dilation

    while (true) {
        int x0 = max(bx0 - tneed, 0), x1 = min(bx1 + tneed, G - 1);
        int y0 = max(by0 - tneed, 0), y1 = min(by1 + tneed, G - 1);
        int z0 = max(bz0 - tneed, 0), z1 = min(bz1 + tneed, G - 1);
        for (int cbz = z0 >> 2; cbz <= z1 >> 2; ++cbz) {
            for (int cby = y0 >> 2; cby <= y1 >> 2; ++cby) {
                for (int cbx = x0 >> 2; cbx <= x1 >> 2; ++cbx) {
                    if (CO[(cbz * Gc + cby) * Gc + cbx] == 0) continue;
                    int fz0 = max(cbz * 4, z0), fz1 = min(cbz * 4 + 3, z1);
                    int fy0 = max(cby * 4, y0), fy1 = min(cby * 4 + 3, y1);
                    int fx0 = max(cbx * 4, x0), fx1 = min(cbx * 4 + 3, x1);
                    for (int fz = fz0; fz <= fz1; ++fz) {
                        int dz = fz < bz0 ? bz0 - fz : (fz > bz1 ? fz - bz1 : 0);
                        for (int fy = fy0; fy <= fy1; ++fy) {
                            int dy = fy < by0 ? by0 - fy : (fy > by1 ? fy - by1 : 0);
                            int dzy = max(dz, dy);
                            for (int fx = fx0; fx <= fx1; ++fx) {
                                int dx = fx < bx0 ? bx0 - fx : (fx > bx1 ? fx - bx1 : 0);
                                int cd = max(dzy, dx);
                                if (cd <= km) continue;    // already scanned
                                int2 se = META[(fz * G + fy) * G + fx];
                                int j = se.x;
                                for (; j + 2 <= se.y; j += 2) {
                                    float4 t0 = T[j], t1 = T[j + 1];
                                    float a0 = fmaf(nx, t0.x, t0.w);
                                    a0 = fmaf(ny, t0.y, a0);
                                    a0 = fmaf(nz, t0.z, a0);
                                    float a1 = fmaf(nx, t1.x, t1.w);
                                    a1 = fmaf(ny, t1.y, a1);
                                    a1 = fmaf(nz, t1.z, a1);
                                    best = fminf(best, fminf(a0, a1)); // v_min3
                                }
                                if (j < se.y) {
                                    float4 t0 = T[j];
                                    float a0 = fmaf(nx, t0.x, t0.w);
                                    a0 = fmaf(ny, t0.y, a0);
                                    a0 = fmaf(nz, t0.z, a0);
                                    best = fminf(best, a0);
                                }
                            }
                        }
                    }
                }
            }
        }
        km = tneed;
        if (km >= G) break;
        // Required dilation: smallest k with k*W >= this lane's best dist.
        float d2 = wq + best;
        float dc = sqrtf(fmaxf(d2, 0.0f));
        int req = (dc > 1e30f) ? G : (int)(dc * invw) + 1;  // strictly > dc/W
        #pragma unroll
        for (int off = 32; off; off >>= 1) req = max(req, __shfl_xor(req, off));
        req = __builtin_amdgcn_readfirstlane(req);
        req = min(req, G);
        if (req <= km) break;
        tneed = min(req, km + max(km, 2));         // bounded growth per pass
    }

    dmin[i] = sqrtf(fmaxf(wq + best, 0.0f));
}

// ---- 5. per-batch means (sorted order is fine: mean is order-invariant) ----
__global__ __launch_bounds__(BLOCK) void chamfer_finalize(
        const float* __restrict__ dmin, float* __restrict__ out) {
    const int b = blockIdx.x, t = threadIdx.x;
    float s = 0.0f;
    for (int j = t; j < NPTS; j += BLOCK)
        s += dmin[b * NPTS + j] + dmin[NSIDE + b * NPTS + j];
    __shared__ float red[BLOCK];
    red[t] = s;
    __syncthreads();
    for (int off = BLOCK / 2; off > 0; off >>= 1) {
        if (t < off) red[t] += red[t + off];
        __syncthreads();
    }
    if (t == 0) out[b] = red[0] / (2.0f * (float)NPTS);
}

extern "C" void kernel_launch(void* const* d_in, const int* in_sizes, int n_in,
                              void* d_out, int out_size, void* d_ws, size_t ws_size,
                              hipStream_t stream) {
    const float* pred = (const float*)d_in[0];
    const float* tgtp = (const float*)d_in[1];
    float* out = (float*)d_out;

    // Grid resolution by available workspace (all choices exact).
    int G;
    if      (ws_size >= (size_t)14 * 1024 * 1024) G = 32;
    else if (ws_size >= (size_t)5 * 1024 * 1024)  G = 16;
    else                                          G = 8;
    const int G3 = G * G * G;
    const int Gc = G / 4;
    const int Gc3 = Gc * Gc * Gc;
    const float lo = GRID_LO;
    const float W = (GRID_HI - GRID_LO) / (float)G;
    const float invw = 1.0f / W;

    // ws layout: sortedP 1MB | sortedT 1MB | dmin 512KB |
    //            counts 16*G3*4 | ccoarse 16*Gc3*4 | cstart | ccur | cmeta(int2)
    char* ws = (char*)d_ws;
    float4* sortedP = (float4*)ws;
    float4* sortedT = (float4*)(ws + (size_t)NSIDE * 16);
    float* dmin = (float*)(ws + (size_t)2 * NSIDE * 16);
    char* p = ws + (size_t)2 * NSIDE * 16 + (size_t)NTOT * 4;
    int* counts = (int*)p;                 p += (size_t)16 * G3 * 4;
    int* ccoarse = (int*)p;                p += (size_t)16 * Gc3 * 4;
    int* cstart = (int*)p;                 p += (size_t)16 * G3 * 4;
    int* ccur = (int*)p;                   p += (size_t)16 * G3 * 4;
    int2* cmeta = (int2*)p;

    // Zero counts + ccoarse (contiguous).
    hipMemsetAsync(counts, 0, (size_t)16 * (G3 + Gc3) * 4, stream);

    bin_count<<<NTOT / BLOCK, BLOCK, 0, stream>>>(pred, tgtp, counts, ccoarse,
                                                  G, G3, Gc, Gc3, lo, invw);
    scan_cells<<<16, 1024, 0, stream>>>(counts, cstart, ccur, G3);
    bin_scatter<<<NTOT / BLOCK, BLOCK, 0, stream>>>(pred, tgtp, ccur, sortedP, sortedT,
                                                    G, G3, lo, invw);
    // ccur now holds per-cell END offsets.
    build_meta<<<(16 * G3 + BLOCK - 1) / BLOCK, BLOCK, 0, stream>>>(cstart, ccur,
                                                                    cmeta, 16 * G3);
    query_min<<<NTOT / BLOCK, BLOCK, 0, stream>>>(sortedP, sortedT, cmeta, ccoarse,
                                                  dmin, G, G3, Gc, Gc3, lo, W, invw);
    chamfer_finalize<<<BB, BLOCK, 0, stream>>>(dmin, out);
}

// Round 8
// 130.248 us; speedup vs baseline: 27.7981x; 27.7981x over previous
//
#include <hip/hip_runtime.h>
#include <math.h>

// Problem constants (fixed by setup_inputs): B=8, N=M=8192, D=3, fp32.
// Fused both-direction chamfer via systolic lane rotation:
//   - thread owns 8 query rows (pred side), lane owns 1 target (tgt side)
//   - targets + their running col-min rotate lane->lane via ds_bpermute
//   - d^2 = (|q|^2+|t|^2) - 2 q.t computed ONCE per pair, feeds BOTH the
//     row-min (pred->tgt) and the traveling col-min (tgt->pred)
#define BB 8
#define NPTS 8192
#define NSIDE (BB * NPTS)     // 65536 points per side

#define BLOCK 256
#define RROWS 8                    // query rows per thread
#define QTILE (BLOCK * RROWS)      // 2048 queries per block
#define NQT (NPTS / QTILE)         // 4 q-tiles per batch
#define TGB 2                      // target groups (of 64) per block
#define NTC (NPTS / (64 * TGB))    // 64 t-chunks per batch

// Monotone float->int key so signed-int atomicMin orders like float.
__device__ __forceinline__ int enc_key(float v) {
    int b = __float_as_int(v);
    return b >= 0 ? b : (b ^ 0x7fffffff);
}
__device__ __forceinline__ float dec_key(int k) {
    int b = k >= 0 ? k : (k ^ 0x7fffffff);
    return __int_as_float(b);
}

// grid = (t-chunks, q-tiles, batches). Keys hold enc(full d^2 min).
__global__ __launch_bounds__(BLOCK) void chamfer_rot(
        const float* __restrict__ pred, const float* __restrict__ tgt,
        int* __restrict__ rk, int* __restrict__ ck) {
    const int b = blockIdx.z;
    const int qt = blockIdx.y;
    const int tc = blockIdx.x;
    const int t = threadIdx.x;
    const int lane = t & 63;

    // Load this thread's 8 queries from raw input; pre-negate.
    float nx[RROWS], ny[RROWS], nz[RROWS], wq[RROWS], rmin[RROWS];
    const float* qp = pred + (size_t)b * NPTS * 3;
    #pragma unroll
    for (int r = 0; r < RROWS; ++r) {
        int qi = qt * QTILE + r * BLOCK + t;
        float x = qp[qi * 3 + 0], y = qp[qi * 3 + 1], z = qp[qi * 3 + 2];
        nx[r] = -2.0f * x;
        ny[r] = -2.0f * y;
        nz[r] = -2.0f * z;
        wq[r] = fmaf(x, x, fmaf(y, y, z * z));
        rmin[r] = INFINITY;
    }

    const int rot = ((lane + 1) & 63) * 4;     // bpermute byte address
    const float* tp = tgt + (size_t)b * NPTS * 3;

    #pragma unroll
    for (int g = 0; g < TGB; ++g) {
        const int tbase = (tc * TGB + g) * 64;
        const int ti = tbase + lane;           // this lane's home target
        float tx = tp[ti * 3 + 0], ty = tp[ti * 3 + 1], tz = tp[ti * 3 + 2];
        float tw = fmaf(tx, tx, fmaf(ty, ty, tz * tz));
        float cmin = INFINITY;                 // travels WITH the target

        #pragma unroll 4
        for (int s = 0; s < 64; ++s) {
            float a[RROWS];
            #pragma unroll
            for (int r = 0; r < RROWS; ++r) {
                float v = fmaf(nx[r], tx, tw + wq[r]);   // d^2 (full)
                v = fmaf(ny[r], ty, v);
                v = fmaf(nz[r], tz, v);
                a[r] = v;
                rmin[r] = fminf(rmin[r], v);             // row side
            }
            float m1 = fminf(fminf(a[0], a[1]), fminf(a[2], a[3]));
            float m2 = fminf(fminf(a[4], a[5]), fminf(a[6], a[7]));
            cmin = fminf(cmin, fminf(m1, m2));           // col side
            // rotate target + its col-min one lane (LDS pipe, hidden by VALU)
            tx = __int_as_float(__builtin_amdgcn_ds_bpermute(rot, __float_as_int(tx)));
            ty = __int_as_float(__builtin_amdgcn_ds_bpermute(rot, __float_as_int(ty)));
            tz = __int_as_float(__builtin_amdgcn_ds_bpermute(rot, __float_as_int(tz)));
            tw = __int_as_float(__builtin_amdgcn_ds_bpermute(rot, __float_as_int(tw)));
            cmin = __int_as_float(__builtin_amdgcn_ds_bpermute(rot, __float_as_int(cmin)));
        }
        // After 64 rotations everything is home: cmin belongs to target ti.
        atomicMin(&ck[(size_t)b * NPTS + ti], enc_key(cmin));
    }

    #pragma unroll
    for (int r = 0; r < RROWS; ++r) {
        int qi = qt * QTILE + r * BLOCK + t;
        atomicMin(&rk[(size_t)b * NPTS + qi], enc_key(rmin[r]));
    }
}

// Keys hold full d^2 mins. 32 slice-blocks per batch; atomicAdd into out[b].
#define FSLICE 32
__global__ __launch_bounds__(BLOCK) void chamfer_finalize(
        const int* __restrict__ rk, const int* __restrict__ ck,
        float* __restrict__ out) {
    const int b = blockIdx.x / FSLICE;
    const int s = blockIdx.x % FSLICE;
    const int t = threadIdx.x;
    const int span = NPTS / FSLICE;            // 256
    const int i = b * NPTS + s * span + t;
    float v = 0.0f;
    if (t < span)                              // span == BLOCK anyway
        v = sqrtf(fmaxf(dec_key(rk[i]), 0.0f)) + sqrtf(fmaxf(dec_key(ck[i]), 0.0f));
    __shared__ float red[BLOCK];
    red[t] = v * (0.5f / (float)NPTS);
    __syncthreads();
    for (int off = BLOCK / 2; off > 0; off >>= 1) {
        if (t < off) red[t] += red[t + off];
        __syncthreads();
    }
    if (t == 0) atomicAdd(&out[b], red[0]);
}

extern "C" void kernel_launch(void* const* d_in, const int* in_sizes, int n_in,
                              void* d_out, int out_size, void* d_ws, size_t ws_size,
                              hipStream_t stream) {
    const float* pred = (const float*)d_in[0];
    const float* tgtp = (const float*)d_in[1];
    float* out = (float*)d_out;

    // ws: rk (256 KB) | ck (256 KB)
    int* rk = (int*)d_ws;
    int* ck = rk + NSIDE;

    hipMemsetAsync(rk, 0x7F, (size_t)2 * NSIDE * sizeof(int), stream);  // +inf keys
    hipMemsetAsync(out, 0, (size_t)BB * sizeof(float), stream);

    // 64 t-chunks x 4 q-tiles x 8 batches = 2048 blocks (8 per CU).
    chamfer_rot<<<dim3(NTC, NQT, BB), BLOCK, 0, stream>>>(pred, tgtp, rk, ck);

    chamfer_finalize<<<BB * FSLICE, BLOCK, 0, stream>>>(rk, ck, out);
}

// Round 9
// 124.841 us; speedup vs baseline: 29.0020x; 1.0433x over previous
//
#include <hip/hip_runtime.h>
#include <math.h>

// Problem constants (fixed by setup_inputs): B=8, N=M=8192, D=3, fp32.
// MFMA-based chamfer: d^2 = wq + tw - 2 q.t computed per 32x32 tile by one
// v_mfma_f32_32x32x16_bf16, with fp32 values split into bf16 hi/lo pairs and
// cross terms laid out along K (13 of 16 slots). One pass feeds BOTH min
// directions: row-mins in registers, col-mins via LDS atomicMin.
#define BB 8
#define NPTS 8192
#define NSIDE (BB * NPTS)     // 65536 points per side

#define BLOCK 256
#define WARPS 4               // waves per block; each wave owns 32 query rows
#define ROWSB (32 * WARPS)    // 128 rows per block
#define TCHUNK 2048           // targets per block
#define NTILES (TCHUNK / 32)  // 64 MFMA tiles per wave

#define INF_KEY 0x7F7F7F7F

typedef short bf16x8 __attribute__((ext_vector_type(8)));
typedef float f32x16 __attribute__((ext_vector_type(16)));

// Monotone float->int key so signed-int atomicMin orders like float.
__device__ __forceinline__ int enc_key(float v) {
    int b = __float_as_int(v);
    return b >= 0 ? b : (b ^ 0x7fffffff);
}
__device__ __forceinline__ float dec_key(int k) {
    int b = k >= 0 ? k : (k ^ 0x7fffffff);
    return __int_as_float(b);
}

__device__ __forceinline__ unsigned short f2bf(float f) {   // RNE fp32->bf16
    unsigned u = __float_as_uint(f);
    return (unsigned short)((u + 0x7FFFu + ((u >> 16) & 1u)) >> 16);
}
__device__ __forceinline__ float bfhi(float f, unsigned short* bits) {
    unsigned short h = f2bf(f);
    *bits = h;
    return __uint_as_float(((unsigned)h) << 16);
}

// Pack each point into a 16-slot bf16 K-vector (32 B). Slot pairing (A slot k
// multiplies B slot k):  k0..2: x (h*h, h*l, l*h)  k3..5: y  k6..8: z
// k9,10: wq_h*1, wq_l*1   k11,12: 1*tw_h, 1*tw_l   k13..15: 0.
// A-form holds a = -2*p (pred side); B-form holds b = t (tgt side).
__global__ __launch_bounds__(BLOCK) void chamfer_pack(
        const float* __restrict__ pred, const float* __restrict__ tgt,
        unsigned short* __restrict__ pA, unsigned short* __restrict__ pB,
        int* __restrict__ rk, int* __restrict__ ck, float* __restrict__ out) {
    int i = blockIdx.x * BLOCK + threadIdx.x;      // 0..NSIDE-1
    const unsigned short one = 0x3F80;             // bf16(1.0)

    {   // ---- A-form from pred ----
        float x = pred[(size_t)i * 3 + 0], y = pred[(size_t)i * 3 + 1],
              z = pred[(size_t)i * 3 + 2];
        float wq = fmaf(x, x, fmaf(y, y, z * z));
        float ax = -2.0f * x, ay = -2.0f * y, az = -2.0f * z;
        unsigned short hx, hy, hz, hw;
        float fhx = bfhi(ax, &hx), fhy = bfhi(ay, &hy), fhz = bfhi(az, &hz);
        float fhw = bfhi(wq, &hw);
        unsigned short lx = f2bf(ax - fhx), ly = f2bf(ay - fhy),
                       lz = f2bf(az - fhz), lw = f2bf(wq - fhw);
        unsigned short s[16] = {hx, hx, lx, hy, hy, ly, hz, hz, lz,
                                hw, lw, one, one, 0, 0, 0};
        uint4* dst = (uint4*)(pA + (size_t)i * 16);
        uint4 w0 = {(unsigned)s[0] | ((unsigned)s[1] << 16),
                    (unsigned)s[2] | ((unsigned)s[3] << 16),
                    (unsigned)s[4] | ((unsigned)s[5] << 16),
                    (unsigned)s[6] | ((unsigned)s[7] << 16)};
        uint4 w1 = {(unsigned)s[8] | ((unsigned)s[9] << 16),
                    (unsigned)s[10] | ((unsigned)s[11] << 16),
                    (unsigned)s[12] | ((unsigned)s[13] << 16),
                    (unsigned)s[14] | ((unsigned)s[15] << 16)};
        dst[0] = w0; dst[1] = w1;
    }
    {   // ---- B-form from tgt ----
        float x = tgt[(size_t)i * 3 + 0], y = tgt[(size_t)i * 3 + 1],
              z = tgt[(size_t)i * 3 + 2];
        float tw = fmaf(x, x, fmaf(y, y, z * z));
        unsigned short hx, hy, hz, hw;
        float fhx = bfhi(x, &hx), fhy = bfhi(y, &hy), fhz = bfhi(z, &hz);
        float fhw = bfhi(tw, &hw);
        unsigned short lx = f2bf(x - fhx), ly = f2bf(y - fhy),
                       lz = f2bf(z - fhz), lw = f2bf(tw - fhw);
        unsigned short s[16] = {hx, lx, hx, hy, ly, hy, hz, lz, hz,
                                one, one, hw, lw, 0, 0, 0};
        uint4* dst = (uint4*)(pB + (size_t)i * 16);
        uint4 w0 = {(unsigned)s[0] | ((unsigned)s[1] << 16),
                    (unsigned)s[2] | ((unsigned)s[3] << 16),
                    (unsigned)s[4] | ((unsigned)s[5] << 16),
                    (unsigned)s[6] | ((unsigned)s[7] << 16)};
        uint4 w1 = {(unsigned)s[8] | ((unsigned)s[9] << 16),
                    (unsigned)s[10] | ((unsigned)s[11] << 16),
                    (unsigned)s[12] | ((unsigned)s[13] << 16),
                    (unsigned)s[14] | ((unsigned)s[15] << 16)};
        dst[0] = w0; dst[1] = w1;
    }
    rk[i] = INF_KEY;
    ck[i] = INF_KEY;
    if (i < BB) out[i] = 0.0f;
}

// grid = (NPTS/TCHUNK, NPTS/ROWSB, BB). Each wave: 32 query rows x TCHUNK
// targets, one MFMA per 32x32 tile. A/B fragment layout (32x32x16):
// lane l supplies point (l&31), K-slots 8*(l>>5)+e. D layout (HW-verified):
// col = l&31, row = (k&3) + 8*(k>>2) + 4*(l>>5).
__global__ __launch_bounds__(BLOCK) void chamfer_mfma(
        const unsigned short* __restrict__ pA, const unsigned short* __restrict__ pB,
        int* __restrict__ rk, int* __restrict__ ck) {
    const int b = blockIdx.z;
    const int tb0 = blockIdx.x * TCHUNK;
    const int rb0 = blockIdx.y * ROWSB;
    const int wave = threadIdx.x >> 6;
    const int lane = threadIdx.x & 63;
    const int lp = lane & 31;            // point index within tile
    const int kh = lane >> 5;            // K half

    __shared__ int colkey[TCHUNK];       // 8 KB: per-block col-min partials
    for (int j = threadIdx.x; j < TCHUNK; j += BLOCK) colkey[j] = INF_KEY;
    __syncthreads();

    const bf16x8* Ap = (const bf16x8*)pA;
    const bf16x8* Bp = (const bf16x8*)pB;
    const bf16x8 afrag = Ap[(size_t)(b * NPTS + rb0 + wave * 32 + lp) * 2 + kh];

    f32x16 zero;
    #pragma unroll
    for (int k = 0; k < 16; ++k) zero[k] = 0.0f;

    float rmin[16];
    #pragma unroll
    for (int k = 0; k < 16; ++k) rmin[k] = INFINITY;

    size_t bidx = (size_t)(b * NPTS + tb0 + lp) * 2 + kh;

    #pragma unroll 2
    for (int tile = 0; tile < NTILES; ++tile) {
        const bf16x8 bfrag = Bp[bidx];
        bidx += 64;                      // 32 points * 2 halves
        f32x16 d = __builtin_amdgcn_mfma_f32_32x32x16_bf16(afrag, bfrag, zero, 0, 0, 0);
        // row side: per-lane partial (this lane's col only)
        #pragma unroll
        for (int k = 0; k < 16; ++k) rmin[k] = fminf(rmin[k], d[k]);
        // col side: min over the 16 rows this lane holds, then LDS-merge
        float c0 = fminf(fminf(d[0], d[1]), fminf(d[2], d[3]));
        float c1 = fminf(fminf(d[4], d[5]), fminf(d[6], d[7]));
        float c2 = fminf(fminf(d[8], d[9]), fminf(d[10], d[11]));
        float c3 = fminf(fminf(d[12], d[13]), fminf(d[14], d[15]));
        float cp = fminf(fminf(c0, c1), fminf(c2, c3));
        atomicMin(&colkey[tile * 32 + lp], enc_key(cp));
    }

    // row reduce: butterfly across the 32 lanes sharing each row-set
    #pragma unroll
    for (int k = 0; k < 16; ++k) {
        #pragma unroll
        for (int off = 1; off <= 16; off <<= 1)
            rmin[k] = fminf(rmin[k], __shfl_xor(rmin[k], off));
    }
    if (lp == 0) {
        #pragma unroll
        for (int k = 0; k < 16; ++k) {
            int row = (k & 3) + 8 * (k >> 2) + 4 * kh;
            atomicMin(&rk[(size_t)b * NPTS + rb0 + wave * 32 + row],
                      enc_key(rmin[k]));
        }
    }

    __syncthreads();
    for (int j = threadIdx.x; j < TCHUNK; j += BLOCK)
        atomicMin(&ck[(size_t)b * NPTS + tb0 + j], colkey[j]);
}

// Keys hold d^2 mins. 32 slice-blocks per batch; atomicAdd into out[b].
#define FSLICE 32
__global__ __launch_bounds__(BLOCK) void chamfer_finalize(
        const int* __restrict__ rk, const int* __restrict__ ck,
        float* __restrict__ out) {
    const int b = blockIdx.x / FSLICE;
    const int s = blockIdx.x % FSLICE;
    const int t = threadIdx.x;
    const int i = b * NPTS + s * (NPTS / FSLICE) + t;
    float v = sqrtf(fmaxf(dec_key(rk[i]), 0.0f)) +
              sqrtf(fmaxf(dec_key(ck[i]), 0.0f));
    __shared__ float red[BLOCK];
    red[t] = v * (0.5f / (float)NPTS);
    __syncthreads();
    for (int off = BLOCK / 2; off > 0; off >>= 1) {
        if (t < off) red[t] += red[t + off];
        __syncthreads();
    }
    if (t == 0) atomicAdd(&out[b], red[0]);
}

extern "C" void kernel_launch(void* const* d_in, const int* in_sizes, int n_in,
                              void* d_out, int out_size, void* d_ws, size_t ws_size,
                              hipStream_t stream) {
    const float* pred = (const float*)d_in[0];
    const float* tgtp = (const float*)d_in[1];
    float* out = (float*)d_out;

    // ws: pA 2MB | pB 2MB | rk 256KB | ck 256KB  (ws_size >= ~14MB per R6/R7)
    char* ws = (char*)d_ws;
    unsigned short* pA = (unsigned short*)ws;
    unsigned short* pB = (unsigned short*)(ws + (size_t)NSIDE * 32);
    int* rk = (int*)(ws + (size_t)2 * NSIDE * 32);
    int* ck = rk + NSIDE;

    chamfer_pack<<<NSIDE / BLOCK, BLOCK, 0, stream>>>(pred, tgtp, pA, pB, rk, ck, out);

    // 4 t-chunks x 64 row-blocks x 8 batches = 2048 blocks (8 per CU).
    chamfer_mfma<<<dim3(NPTS / TCHUNK, NPTS / ROWSB, BB), BLOCK, 0, stream>>>(
        pA, pB, rk, ck);

    chamfer_finalize<<<BB * FSLICE, BLOCK, 0, stream>>>(rk, ck, out);
}